// Round 1
// baseline (1738.366 us; speedup 1.0000x reference)
//
#include <hip/hip_runtime.h>

// GRU: B=32, T=50, N=1024, C=128, H=64. 32768 independent sequences.
// Wave-per-16-sequences, lane j owns hidden element j (and gate rows j, j+64, j+128).
// Weights pre-transposed to d_ws for coalesced per-lane reads.

constexpr int T_ = 50, N_ = 1024, C_ = 128, H_ = 64;
constexpr int S_ = 16;     // sequences per wave
constexpr int WAVES = 2;   // waves per block (block = 128 threads)

__global__ void transpose_w(const float* __restrict__ Wih, const float* __restrict__ Whh,
                            float* __restrict__ WihT, float* __restrict__ WhhT) {
  int i = blockIdx.x * 256 + threadIdx.x;
  if (i < 192 * 128) { int r = i >> 7, k = i & 127; WihT[k * 192 + r] = Wih[i]; }
  if (i < 192 * 64)  { int r = i >> 6, k = i & 63;  WhhT[k * 192 + r] = Whh[i]; }
}

__global__ __launch_bounds__(WAVES * 64, 2) void gru_fused(
    const float* __restrict__ x, const float* __restrict__ WihT,
    const float* __restrict__ WhhT, const float* __restrict__ bih,
    const float* __restrict__ bhh, float* __restrict__ out)
{
  __shared__ float xT[WAVES][C_][S_];  // x transposed: [k][seq] per wave
  __shared__ float hT[WAVES][H_][S_];  // h transposed: [k][seq] per wave
  const int wv   = threadIdx.x >> 6;
  const int lane = threadIdx.x & 63;
  const int grp  = blockIdx.x * WAVES + wv;   // 0..2047
  const int seq0 = grp * S_;                  // 16 consecutive (b,n) pairs, same b
  const int b    = seq0 >> 10;
  const int n0   = seq0 & (N_ - 1);

  // biases for this lane's three gate rows
  const float b_r  = bih[lane]      + bhh[lane];
  const float b_z  = bih[64 + lane] + bhh[64 + lane];
  const float bi_n = bih[128 + lane];
  const float bh_n = bhh[128 + lane];

  float h[S_];
#pragma unroll
  for (int s = 0; s < S_; ++s) h[s] = 0.f;
#pragma unroll
  for (int s = 0; s < S_; ++s) hT[wv][lane][s] = 0.f;

  // x staging mapping: lane -> (seq = lane/4, k0 = (lane%4)*32), 8 x float4 each
  const int lseq = lane >> 2;
  const int lk0  = (lane & 3) << 5;
  const float* xbase = x + ((size_t)b * T_ * N_ + n0) * C_ + lseq * C_ + lk0;

  for (int t = 0; t < T_; ++t) {
    // ---- stage x_t (16 seqs x 128) into LDS transposed ----
    const float* src = xbase + (size_t)t * N_ * C_;
#pragma unroll
    for (int j = 0; j < 8; ++j) {
      float4 v = *reinterpret_cast<const float4*>(src + j * 4);
      int k = lk0 + j * 4;
      xT[wv][k + 0][lseq] = v.x;
      xT[wv][k + 1][lseq] = v.y;
      xT[wv][k + 2][lseq] = v.z;
      xT[wv][k + 3][lseq] = v.w;
    }
    __syncthreads();  // xT ready; hT from previous step ready

    float ai0[S_], ai1[S_], ai2[S_];
    float ah0[S_], ah1[S_], ah2[S_];
#pragma unroll
    for (int s = 0; s < S_; ++s) {
      ai0[s] = 0.f; ai1[s] = 0.f; ai2[s] = 0.f;
      ah0[s] = 0.f; ah1[s] = 0.f; ah2[s] = 0.f;
    }

    // ---- gi = W_ih @ x  (K = 128) ----
#pragma unroll 2
    for (int k = 0; k < C_; ++k) {
      const float w0 = WihT[k * 192 + lane];
      const float w1 = WihT[k * 192 + 64 + lane];
      const float w2 = WihT[k * 192 + 128 + lane];
      const float4 x0 = *reinterpret_cast<const float4*>(&xT[wv][k][0]);
      const float4 x1 = *reinterpret_cast<const float4*>(&xT[wv][k][4]);
      const float4 x2 = *reinterpret_cast<const float4*>(&xT[wv][k][8]);
      const float4 x3 = *reinterpret_cast<const float4*>(&xT[wv][k][12]);
      const float xv[S_] = {x0.x, x0.y, x0.z, x0.w, x1.x, x1.y, x1.z, x1.w,
                            x2.x, x2.y, x2.z, x2.w, x3.x, x3.y, x3.z, x3.w};
#pragma unroll
      for (int s = 0; s < S_; ++s) {
        ai0[s] = fmaf(w0, xv[s], ai0[s]);
        ai1[s] = fmaf(w1, xv[s], ai1[s]);
        ai2[s] = fmaf(w2, xv[s], ai2[s]);
      }
    }

    // ---- gh = W_hh @ h  (K = 64) ----
#pragma unroll 2
    for (int k = 0; k < H_; ++k) {
      const float w0 = WhhT[k * 192 + lane];
      const float w1 = WhhT[k * 192 + 64 + lane];
      const float w2 = WhhT[k * 192 + 128 + lane];
      const float4 h0v = *reinterpret_cast<const float4*>(&hT[wv][k][0]);
      const float4 h1v = *reinterpret_cast<const float4*>(&hT[wv][k][4]);
      const float4 h2v = *reinterpret_cast<const float4*>(&hT[wv][k][8]);
      const float4 h3v = *reinterpret_cast<const float4*>(&hT[wv][k][12]);
      const float hv[S_] = {h0v.x, h0v.y, h0v.z, h0v.w, h1v.x, h1v.y, h1v.z, h1v.w,
                            h2v.x, h2v.y, h2v.z, h2v.w, h3v.x, h3v.y, h3v.z, h3v.w};
#pragma unroll
      for (int s = 0; s < S_; ++s) {
        ah0[s] = fmaf(w0, hv[s], ah0[s]);
        ah1[s] = fmaf(w1, hv[s], ah1[s]);
        ah2[s] = fmaf(w2, hv[s], ah2[s]);
      }
    }

    // ---- gates + state update ----
#pragma unroll
    for (int s = 0; s < S_; ++s) {
      const float r = __builtin_amdgcn_rcpf(1.f + __expf(-(ai0[s] + ah0[s] + b_r)));
      const float z = __builtin_amdgcn_rcpf(1.f + __expf(-(ai1[s] + ah1[s] + b_z)));
      const float npre = ai2[s] + bi_n + r * (ah2[s] + bh_n);
      const float nn = 1.f - 2.f * __builtin_amdgcn_rcpf(__expf(2.f * npre) + 1.f);  // tanh
      h[s] = (1.f - z) * nn + z * h[s];
    }
    __syncthreads();  // all reads of hT (this step) done
#pragma unroll
    for (int s = 0; s < S_; ++s) hT[wv][lane][s] = h[s];
  }

  // out[b][n0+s][lane]
  float* op = out + ((size_t)(b * N_ + n0)) * H_ + lane;
#pragma unroll
  for (int s = 0; s < S_; ++s) op[s * H_] = h[s];
}

extern "C" void kernel_launch(void* const* d_in, const int* in_sizes, int n_in,
                              void* d_out, int out_size, void* d_ws, size_t ws_size,
                              hipStream_t stream) {
  const float* chars = (const float*)d_in[0];
  const float* Wih   = (const float*)d_in[1];
  const float* Whh   = (const float*)d_in[2];
  const float* bih   = (const float*)d_in[3];
  const float* bhh   = (const float*)d_in[4];

  float* WihT = (float*)d_ws;            // 128*192 floats
  float* WhhT = WihT + 192 * 128;        // 64*192 floats  (total 147456 B of ws)

  transpose_w<<<96, 256, 0, stream>>>(Wih, Whh, WihT, WhhT);

  // 2048 wave-tasks (16 seqs each), 2 waves per block -> 1024 blocks
  gru_fused<<<1024, WAVES * 64, 0, stream>>>(chars, WihT, WhhT, bih, bhh, (float*)d_out);
}

// Round 2
// 252.579 us; speedup vs baseline: 6.8825x; 6.8825x over previous
//
#include <hip/hip_runtime.h>

// GRU B=32,T=50,N=1024,C=128,H=64 via fp16 MFMA (16x16x32), fp32 accum.
// 256 blocks x 8 waves; each wave privately owns 16 sequences for all 50 steps
// -> no __syncthreads in the main loop. Weights fp16 in LDS (XOR-swizzled),
// x A-frags loaded direct from global with 1-step prefetch, h in 2KB/wave LDS.

typedef _Float16 half8 __attribute__((ext_vector_type(8)));
typedef float f32x4 __attribute__((ext_vector_type(4)));

constexpr int T_ = 50, N_ = 1024, C_ = 128, H_ = 64;
// LDS byte map
constexpr int WIH_OFF = 0;       // 192 rows x 128 f16 (256 B/row) = 49152 B
constexpr int WHH_OFF = 49152;   // 192 rows x  64 f16 (128 B/row) = 24576 B
constexpr int H_OFF   = 73728;   // 8 waves x [16][64] f16 (2 KB)  = 16384 B
constexpr int LDS_BYTES = 90112;

__global__ void prep_weights(const float* __restrict__ Wih, const float* __restrict__ Whh,
                             _Float16* __restrict__ w16) {
  int i = blockIdx.x * 256 + threadIdx.x;
  if (i < 192 * 128) w16[i] = (_Float16)Wih[i];
  if (i < 192 * 64)  w16[24576 + i] = (_Float16)Whh[i];
}

__global__ __launch_bounds__(512, 2) void gru_mfma(
    const float* __restrict__ x, const _Float16* __restrict__ w16,
    const float* __restrict__ bih, const float* __restrict__ bhh,
    float* __restrict__ out)
{
  __shared__ __align__(16) char lds[LDS_BYTES];
  const int tid = threadIdx.x;

  // ---- stage fp16 weights into LDS, XOR-swizzled rows; zero h bufs ----
  {
    const _Float16* wih = w16;
    const _Float16* whh = w16 + 24576;
#pragma unroll
    for (int rep = 0; rep < 6; ++rep) {            // Wih: 3072 16B chunks
      int i = tid + rep * 512;
      int row = i >> 4;                            // 16 chunks per 256B row
      uint32_t byte = ((uint32_t)i << 4) ^ ((row & 7) << 4);
      *(half8*)(lds + WIH_OFF + byte) = *(const half8*)(wih + i * 8);
    }
#pragma unroll
    for (int rep = 0; rep < 3; ++rep) {            // Whh: 1536 16B chunks
      int i = tid + rep * 512;
      int row = i >> 3;                            // 8 chunks per 128B row
      uint32_t byte = ((uint32_t)i << 4) ^ ((row & 7) << 4);
      *(half8*)(lds + WHH_OFF + byte) = *(const half8*)(whh + i * 8);
    }
    half8 zz = {};
#pragma unroll
    for (int rep = 0; rep < 2; ++rep)
      *(half8*)(lds + H_OFF + (tid + rep * 512) * 16) = zz;
  }
  __syncthreads();   // the ONLY barrier

  const int wv = tid >> 6, lane = tid & 63;
  const int c = lane & 15, g = lane >> 4;
  const uint32_t hbase = H_OFF + wv * 2048;
  const int gseq0 = blockIdx.x * 128 + wv * 16;    // 16 seqs, same batch b
  const int b = gseq0 >> 10, n0 = gseq0 & (N_ - 1);
  const float* xrow = x + ((size_t)b * T_ * N_ + n0 + c) * C_;  // A row = c
  const size_t stepstride = (size_t)N_ * C_;

  // per-lane biases for hidden cols j = j4*16 + c
  float br[4], bz[4], bin[4], bhn[4];
#pragma unroll
  for (int j4 = 0; j4 < 4; ++j4) {
    int j = j4 * 16 + c;
    br[j4]  = bih[j] + bhh[j];
    bz[j4]  = bih[64 + j] + bhh[64 + j];
    bin[j4] = bih[128 + j];
    bhn[j4] = bhh[128 + j];
  }

  float hreg[16];
#pragma unroll
  for (int i = 0; i < 16; ++i) hreg[i] = 0.f;

  // prologue: load x(t=0); lane loads row c, k-chunks ks*32+g*8 .. +8
  float4 raw[8];
#pragma unroll
  for (int ks = 0; ks < 4; ++ks)
#pragma unroll
    for (int hf = 0; hf < 2; ++hf)
      raw[ks * 2 + hf] = *(const float4*)(xrow + ks * 32 + g * 8 + hf * 4);

  for (int t = 0; t < T_; ++t) {
    // convert raw -> fp16 A-frags (RN); implicit vmcnt wait for step t's x
    half8 xf[4];
#pragma unroll
    for (int ks = 0; ks < 4; ++ks) {
      const float4 lo = raw[ks * 2], hi = raw[ks * 2 + 1];
      xf[ks][0] = (_Float16)lo.x; xf[ks][1] = (_Float16)lo.y;
      xf[ks][2] = (_Float16)lo.z; xf[ks][3] = (_Float16)lo.w;
      xf[ks][4] = (_Float16)hi.x; xf[ks][5] = (_Float16)hi.y;
      xf[ks][6] = (_Float16)hi.z; xf[ks][7] = (_Float16)hi.w;
    }
    // prefetch x(t+1): in flight across this whole step
    {
      const int tn = (t + 1 < T_) ? t + 1 : T_ - 1;
      const float* xp = xrow + (size_t)tn * stepstride;
#pragma unroll
      for (int ks = 0; ks < 4; ++ks)
#pragma unroll
        for (int hf = 0; hf < 2; ++hf)
          raw[ks * 2 + hf] = *(const float4*)(xp + ks * 32 + g * 8 + hf * 4);
    }

    f32x4 Orz[8], Oin[4], Ohn[4];
#pragma unroll
    for (int i = 0; i < 8; ++i) Orz[i] = (f32x4){0.f, 0.f, 0.f, 0.f};
#pragma unroll
    for (int i = 0; i < 4; ++i) { Oin[i] = (f32x4){0.f, 0.f, 0.f, 0.f};
                                  Ohn[i] = (f32x4){0.f, 0.f, 0.f, 0.f}; }

    // ---- x part: K=128 (4 k-steps), Wih rows 0..127 (r,z) and 128..191 (n) ----
#pragma unroll
    for (int ks = 0; ks < 4; ++ks) {
      const half8 a = xf[ks];
#pragma unroll
      for (int ct = 0; ct < 8; ++ct) {
        const int row = ct * 16 + c;
        const uint32_t byte = (uint32_t)(WIH_OFF + row * 256 + ks * 64 + g * 16) ^ ((row & 7) << 4);
        Orz[ct] = __builtin_amdgcn_mfma_f32_16x16x32_f16(a, *(const half8*)(lds + byte), Orz[ct], 0, 0, 0);
      }
#pragma unroll
      for (int ct = 0; ct < 4; ++ct) {
        const int row = 128 + ct * 16 + c;
        const uint32_t byte = (uint32_t)(WIH_OFF + row * 256 + ks * 64 + g * 16) ^ ((row & 7) << 4);
        Oin[ct] = __builtin_amdgcn_mfma_f32_16x16x32_f16(a, *(const half8*)(lds + byte), Oin[ct], 0, 0, 0);
      }
    }
    // ---- h part: K=64 (2 k-steps), Whh rows 0..127 (r,z) and 128..191 (n) ----
#pragma unroll
    for (int ks2 = 0; ks2 < 2; ++ks2) {
      const uint32_t abyte = (hbase + c * 128 + ks2 * 64 + g * 16) ^ ((c & 7) << 4);
      const half8 a = *(const half8*)(lds + abyte);
#pragma unroll
      for (int ct = 0; ct < 8; ++ct) {
        const int row = ct * 16 + c;
        const uint32_t byte = (uint32_t)(WHH_OFF + row * 128 + ks2 * 64 + g * 16) ^ ((row & 7) << 4);
        Orz[ct] = __builtin_amdgcn_mfma_f32_16x16x32_f16(a, *(const half8*)(lds + byte), Orz[ct], 0, 0, 0);
      }
#pragma unroll
      for (int ct = 0; ct < 4; ++ct) {
        const int row = 128 + ct * 16 + c;
        const uint32_t byte = (uint32_t)(WHH_OFF + row * 128 + ks2 * 64 + g * 16) ^ ((row & 7) << 4);
        Ohn[ct] = __builtin_amdgcn_mfma_f32_16x16x32_f16(a, *(const half8*)(lds + byte), Ohn[ct], 0, 0, 0);
      }
    }

    // ---- gates: lane l holds O(seq = g*4+v, col = j4*16+c) in frag regs ----
#pragma unroll
    for (int v = 0; v < 4; ++v) {
#pragma unroll
      for (int j4 = 0; j4 < 4; ++j4) {
        const float rp = Orz[j4][v] + br[j4];
        const float zp = Orz[4 + j4][v] + bz[j4];
        const float r = __builtin_amdgcn_rcpf(1.f + __expf(-rp));
        const float z = __builtin_amdgcn_rcpf(1.f + __expf(-zp));
        const float np = Oin[j4][v] + bin[j4] + r * (Ohn[j4][v] + bhn[j4]);
        const float nn = 1.f - 2.f * __builtin_amdgcn_rcpf(__expf(2.f * np) + 1.f);
        const float hn = (1.f - z) * nn + z * hreg[v * 4 + j4];
        hreg[v * 4 + j4] = hn;
        const int s = g * 4 + v;
        const uint32_t byte = (hbase + s * 128 + (j4 * 16 + c) * 2) ^ ((s & 7) << 4);
        *(_Float16*)(lds + byte) = (_Float16)hn;   // wave-local; DS in-order
      }
    }
  }

  // ---- store final h (fp32 register copy) ----
#pragma unroll
  for (int v = 0; v < 4; ++v) {
    const int s = g * 4 + v;
#pragma unroll
    for (int j4 = 0; j4 < 4; ++j4)
      out[(size_t)(gseq0 + s) * H_ + j4 * 16 + c] = hreg[v * 4 + j4];
  }
}

extern "C" void kernel_launch(void* const* d_in, const int* in_sizes, int n_in,
                              void* d_out, int out_size, void* d_ws, size_t ws_size,
                              hipStream_t stream) {
  const float* chars = (const float*)d_in[0];
  const float* Wih   = (const float*)d_in[1];
  const float* Whh   = (const float*)d_in[2];
  const float* bih   = (const float*)d_in[3];
  const float* bhh   = (const float*)d_in[4];

  _Float16* w16 = (_Float16*)d_ws;   // 36864 f16 = 73728 B

  prep_weights<<<144, 256, 0, stream>>>(Wih, Whh, w16);
  gru_mfma<<<256, 512, 0, stream>>>(chars, w16, bih, bhh, (float*)d_out);
}

// Round 3
// 231.666 us; speedup vs baseline: 7.5038x; 1.0903x over previous
//
#include <hip/hip_runtime.h>

// GRU B=32,T=50,N=1024,C=128,H=64 via fp16 MFMA 32x32x16, fp32 accum.
// 256 blocks x 4 waves (1 wave/SIMD); each wave privately owns 32 sequences for
// all 50 steps -> no barriers in the main loop. Wih fp16 in LDS (256B rows,
// (row&15)<<4 XOR swizzle); Whh held entirely in registers (24 B-frags);
// x A-frags loaded direct from global with 1-step prefetch; h in LDS (fp16,
// swizzled) + fp32 carry in registers for the z*h blend path.

typedef _Float16 half8 __attribute__((ext_vector_type(8)));
typedef float f32x16 __attribute__((ext_vector_type(16)));

constexpr int T_ = 50, N_ = 1024, C_ = 128, H_ = 64;
constexpr int WIH_OFF = 0;       // 192 rows x 256B (128 f16)          = 49152 B
constexpr int H_OFF   = 49152;   // 4 waves x 32 rows x 256B (padded)  = 32768 B
constexpr int LDS_BYTES = 81920;

__global__ void prep_weights(const float* __restrict__ Wih, const float* __restrict__ Whh,
                             _Float16* __restrict__ w16) {
  int i = blockIdx.x * 256 + threadIdx.x;
  if (i < 192 * 128) w16[i] = (_Float16)Wih[i];
  if (i < 192 * 64)  w16[24576 + i] = (_Float16)Whh[i];
}

__device__ __forceinline__ float sigm(float x) {
  return __builtin_amdgcn_rcpf(1.f + __expf(-x));
}

__global__ __launch_bounds__(256, 1) void gru_mfma32(
    const float* __restrict__ x, const _Float16* __restrict__ w16,
    const float* __restrict__ bih, const float* __restrict__ bhh,
    float* __restrict__ out)
{
  __shared__ __align__(16) char lds[LDS_BYTES];
  const int tid = threadIdx.x;

  // ---- stage Wih into LDS (256B rows, granule ^= row&15); zero h bufs ----
  {
    const _Float16* wih = w16;
#pragma unroll
    for (int rep = 0; rep < 12; ++rep) {           // 3072 16B chunks
      int i = tid + rep * 256;
      int row = i >> 4, gr = i & 15;
      uint32_t byte = (uint32_t)row * 256 + (uint32_t)((gr ^ (row & 15)) << 4);
      *(half8*)(lds + WIH_OFF + byte) = *(const half8*)(wih + i * 8);
    }
    half8 zz = {};
#pragma unroll
    for (int rep = 0; rep < 8; ++rep)
      *(half8*)(lds + H_OFF + tid * 128 + rep * 16) = zz;
  }
  __syncthreads();   // the ONLY barrier

  const int wv = tid >> 6, lane = tid & 63;
  const int c32 = lane & 31, hf = lane >> 5;       // B/A col|row = c32, k-half = hf
  const int sw15 = c32 & 15;
  const uint32_t hbase = H_OFF + wv * 8192;
  const int gseq0 = blockIdx.x * 128 + wv * 32;    // 32 seqs, same batch b
  const int b = gseq0 >> 10, n0 = gseq0 & (N_ - 1);

  // ---- Whh B-frags: gathered once from global into registers ----
  const _Float16* whh = w16 + 24576;
  half8 wf[6][4];
#pragma unroll
  for (int ct = 0; ct < 6; ++ct)
#pragma unroll
    for (int ks = 0; ks < 4; ++ks)
      wf[ct][ks] = *(const half8*)(whh + (ct * 32 + c32) * 64 + ks * 16 + hf * 8);

  // ---- per-lane biases: hidden j = jj*32 + c32 ----
  float br[2], bz[2], bin_[2], bhn_[2];
#pragma unroll
  for (int jj = 0; jj < 2; ++jj) {
    int j = jj * 32 + c32;
    br[jj]   = bih[j] + bhh[j];
    bz[jj]   = bih[64 + j] + bhh[64 + j];
    bin_[jj] = bih[128 + j];
    bhn_[jj] = bhh[128 + j];
  }

  float hr[32];                                    // fp32 h carry, [jj*16+reg]
#pragma unroll
  for (int i = 0; i < 32; ++i) hr[i] = 0.f;

  // A-frag: row(seq) = c32, k = hf*8 + ks*16 (+0..7 contiguous)
  const float* xlane = x + ((size_t)b * T_ * N_ + n0 + c32) * C_ + hf * 8;
  const size_t stepstride = (size_t)N_ * C_;

  // Wih B-frag accessor: row = gt*32+c32, k-granule = ks*2+hf, swizzled
#define WIHB(gt, ks) \
  (*(const half8*)(lds + WIH_OFF + (uint32_t)(((gt) * 32 + c32) * 256) + \
                   (uint32_t)(((((ks) * 2 + hf) ^ sw15)) << 4)))
#define MFMA(a, bfrag, acc) __builtin_amdgcn_mfma_f32_32x32x16_f16((a), (bfrag), (acc), 0, 0, 0)

  // prologue: load x(t=0)
  float4 raw[16];
#pragma unroll
  for (int ks = 0; ks < 8; ++ks) {
    raw[ks * 2]     = *(const float4*)(xlane + ks * 16);
    raw[ks * 2 + 1] = *(const float4*)(xlane + ks * 16 + 4);
  }

  for (int t = 0; t < T_; ++t) {
    // convert raw -> fp16 A-frags (waits on step t's x)
    half8 xf[8];
#pragma unroll
    for (int ks = 0; ks < 8; ++ks) {
      const float4 lo = raw[ks * 2], hi = raw[ks * 2 + 1];
      half8 v;
      v[0] = (_Float16)lo.x; v[1] = (_Float16)lo.y;
      v[2] = (_Float16)lo.z; v[3] = (_Float16)lo.w;
      v[4] = (_Float16)hi.x; v[5] = (_Float16)hi.y;
      v[6] = (_Float16)hi.z; v[7] = (_Float16)hi.w;
      xf[ks] = v;
    }

    // h A-frags: row(seq)=c32, k(j)-granule = ks*2+hf, swizzled
    half8 ha[4];
#pragma unroll
    for (int ks = 0; ks < 4; ++ks) {
      uint32_t byte = hbase + (uint32_t)(c32 * 256) + (uint32_t)(((ks * 2 + hf) ^ sw15) << 4);
      ha[ks] = *(const half8*)(lds + byte);
    }

    f32x16 aR0 = {}, aZ0 = {}, aN0 = {}, aH0 = {};
    f32x16 aR1 = {}, aZ1 = {}, aN1 = {}, aH1 = {};

    // ---- group jj0: x-part (Wih tiles 0,2,4) + h-part (Whh tiles 0,2,4) ----
#pragma unroll
    for (int ks = 0; ks < 8; ++ks) aR0 = MFMA(xf[ks], WIHB(0, ks), aR0);
#pragma unroll
    for (int ks = 0; ks < 8; ++ks) aZ0 = MFMA(xf[ks], WIHB(2, ks), aZ0);
#pragma unroll
    for (int ks = 0; ks < 8; ++ks) aN0 = MFMA(xf[ks], WIHB(4, ks), aN0);
#pragma unroll
    for (int ks = 0; ks < 4; ++ks) aR0 = MFMA(ha[ks], wf[0][ks], aR0);
#pragma unroll
    for (int ks = 0; ks < 4; ++ks) aZ0 = MFMA(ha[ks], wf[2][ks], aZ0);
#pragma unroll
    for (int ks = 0; ks < 4; ++ks) aH0 = MFMA(ha[ks], wf[4][ks], aH0);

    // ---- group jj1: x-part (Wih tiles 1,3,5) ----
#pragma unroll
    for (int ks = 0; ks < 8; ++ks) aR1 = MFMA(xf[ks], WIHB(1, ks), aR1);
#pragma unroll
    for (int ks = 0; ks < 8; ++ks) aZ1 = MFMA(xf[ks], WIHB(3, ks), aZ1);
#pragma unroll
    for (int ks = 0; ks < 8; ++ks) aN1 = MFMA(xf[ks], WIHB(5, ks), aN1);

    // ---- prefetch x(t+1): xf regs are dead now; latency covered by h-part + gates ----
    {
      const int tn = (t + 1 < T_) ? t + 1 : T_ - 1;
      const float* xp = xlane + (size_t)tn * stepstride;
#pragma unroll
      for (int ks = 0; ks < 8; ++ks) {
        raw[ks * 2]     = *(const float4*)(xp + ks * 16);
        raw[ks * 2 + 1] = *(const float4*)(xp + ks * 16 + 4);
      }
    }

    // ---- group jj1: h-part (Whh tiles 1,3,5) ----
#pragma unroll
    for (int ks = 0; ks < 4; ++ks) aR1 = MFMA(ha[ks], wf[1][ks], aR1);
#pragma unroll
    for (int ks = 0; ks < 4; ++ks) aZ1 = MFMA(ha[ks], wf[3][ks], aZ1);
#pragma unroll
    for (int ks = 0; ks < 4; ++ks) aH1 = MFMA(ha[ks], wf[5][ks], aH1);

    // ---- gates jj0: D row(seq) = (rg&3)+8*(rg>>2)+4*hf, col(j) = c32 ----
#pragma unroll
    for (int rg = 0; rg < 16; ++rg) {
      const int seq = (rg & 3) + 8 * (rg >> 2) + 4 * hf;
      const float r = sigm(aR0[rg] + br[0]);
      const float z = sigm(aZ0[rg] + bz[0]);
      const float np = aN0[rg] + bin_[0] + r * (aH0[rg] + bhn_[0]);
      const float nn = 1.f - 2.f * __builtin_amdgcn_rcpf(__expf(2.f * np) + 1.f);
      const float hn = (1.f - z) * nn + z * hr[rg];
      hr[rg] = hn;
      const uint32_t gr = (uint32_t)((0 * 4 + (c32 >> 3)) ^ (seq & 15));
      const uint32_t byte = hbase + (uint32_t)(seq * 256) + (gr << 4) + (uint32_t)((c32 * 2) & 15);
      *(_Float16*)(lds + byte) = (_Float16)hn;
    }
    // ---- gates jj1 ----
#pragma unroll
    for (int rg = 0; rg < 16; ++rg) {
      const int seq = (rg & 3) + 8 * (rg >> 2) + 4 * hf;
      const float r = sigm(aR1[rg] + br[1]);
      const float z = sigm(aZ1[rg] + bz[1]);
      const float np = aN1[rg] + bin_[1] + r * (aH1[rg] + bhn_[1]);
      const float nn = 1.f - 2.f * __builtin_amdgcn_rcpf(__expf(2.f * np) + 1.f);
      const float hn = (1.f - z) * nn + z * hr[16 + rg];
      hr[16 + rg] = hn;
      const uint32_t gr = (uint32_t)((1 * 4 + (c32 >> 3)) ^ (seq & 15));
      const uint32_t byte = hbase + (uint32_t)(seq * 256) + (gr << 4) + (uint32_t)((c32 * 2) & 15);
      *(_Float16*)(lds + byte) = (_Float16)hn;
    }
  }

  // ---- store final h (fp32 carry) ----
#pragma unroll
  for (int jj = 0; jj < 2; ++jj)
#pragma unroll
    for (int rg = 0; rg < 16; ++rg) {
      const int seq = (rg & 3) + 8 * (rg >> 2) + 4 * hf;
      out[(size_t)(gseq0 + seq) * H_ + jj * 32 + c32] = hr[jj * 16 + rg];
    }
#undef WIHB
#undef MFMA
}

extern "C" void kernel_launch(void* const* d_in, const int* in_sizes, int n_in,
                              void* d_out, int out_size, void* d_ws, size_t ws_size,
                              hipStream_t stream) {
  const float* chars = (const float*)d_in[0];
  const float* Wih   = (const float*)d_in[1];
  const float* Whh   = (const float*)d_in[2];
  const float* bih   = (const float*)d_in[3];
  const float* bhh   = (const float*)d_in[4];

  _Float16* w16 = (_Float16*)d_ws;   // 36864 f16 = 73728 B

  prep_weights<<<144, 256, 0, stream>>>(Wih, Whh, w16);
  gru_mfma32<<<256, 256, 0, stream>>>(chars, w16, bih, bhh, (float*)d_out);
}